// Round 1
// baseline (2045.263 us; speedup 1.0000x reference)
//
#include <hip/hip_runtime.h>

#define VSZ 32000
#define DSZ 512
#define SSZ 2048
#define NH  8
#define HSZ 64
#define NB  4
#define NROWS (NB*SSZ)   // 8192
#define NT 500           // logsumexp partial tiles per row (250 col-blocks * 2 wave-cols)

typedef unsigned short u16;
typedef __attribute__((ext_vector_type(8))) short bf16x8;
typedef __attribute__((ext_vector_type(4))) float f32x4;

__device__ __forceinline__ u16 f2bf(float f) {
  unsigned int u = __builtin_bit_cast(unsigned int, f);
  u += 0x7fffu + ((u >> 16) & 1u);
  return (u16)(u >> 16);
}

// ---------------- weight prep: transpose W_out [D,V] f32 -> woT [V,D] bf16 ----------------
__global__ __launch_bounds__(256) void k_twout(const float* __restrict__ Wo, u16* __restrict__ woT) {
  __shared__ u16 ts[64 * 74];
  const int vb = blockIdx.x * 64, db = blockIdx.y * 64;
  const int tid = threadIdx.x;
#pragma unroll
  for (int i = 0; i < 16; ++i) {
    int id = tid + i * 256;          // 4096 elems
    int r = id >> 6, c = id & 63;    // r: d-offset, c: v-offset
    ts[r * 74 + c] = f2bf(Wo[(size_t)(db + r) * VSZ + vb + c]);
  }
  __syncthreads();
#pragma unroll
  for (int i = 0; i < 16; ++i) {
    int id = tid + i * 256;
    int v = id >> 6, d = id & 63;
    woT[(size_t)(vb + v) * DSZ + db + d] = ts[d * 74 + v];
  }
}

// ---------- weight prep: Wq/Wk/Wv [H,D,HS] f32 -> [H,HS,D] bf16 (Wq pre-scaled by 1/8) ----------
__global__ __launch_bounds__(256) void k_tqkv(const float* __restrict__ Wq, const float* __restrict__ Wk,
                                              const float* __restrict__ Wv,
                                              u16* __restrict__ wqT, u16* __restrict__ wkT, u16* __restrict__ wvT,
                                              float* __restrict__ loss) {
  const int db = blockIdx.x * 64;      // d tile
  const int h  = blockIdx.y;
  const int z  = blockIdx.z;
  const float* Wsrc = (z == 0) ? Wq : (z == 1) ? Wk : Wv;
  u16* Wdst = (z == 0) ? wqT : (z == 1) ? wkT : wvT;
  const float scale = (z == 0) ? 0.125f : 1.0f;   // fold HS^-0.5 into Q
  __shared__ u16 ts[64 * 74];
  const int tid = threadIdx.x;
#pragma unroll
  for (int i = 0; i < 16; ++i) {
    int id = tid + i * 256;
    int r = id >> 6, c = id & 63;    // r: d-offset, c: e-offset
    ts[r * 74 + c] = f2bf(Wsrc[((size_t)h * DSZ + db + r) * HSZ + c] * scale);
  }
  __syncthreads();
#pragma unroll
  for (int i = 0; i < 16; ++i) {
    int id = tid + i * 256;
    int e = id >> 6, d = id & 63;
    Wdst[((size_t)h * HSZ + e) * DSZ + db + d] = ts[d * 74 + e];
  }
  if (z == 0 && blockIdx.x == 0 && h == 0 && tid == 0) *loss = 0.f;
}

// ---------------- embedding: x[row][d] = tok[idx[row]][d] + pos[s][d] -> bf16 ----------------
__global__ __launch_bounds__(128) void k_embed(const int* __restrict__ index, const float* __restrict__ tok,
                                               const float* __restrict__ pos, u16* __restrict__ xb) {
  const int row = blockIdx.x;        // 0..8191
  const int s = row & (SSZ - 1);
  const int idx = index[row];
  const int d0 = threadIdx.x * 4;
  const float4 t = *(const float4*)(tok + (size_t)idx * DSZ + d0);
  const float4 p = *(const float4*)(pos + (size_t)s * DSZ + d0);
  u16 o0 = f2bf(t.x + p.x), o1 = f2bf(t.y + p.y), o2 = f2bf(t.z + p.z), o3 = f2bf(t.w + p.w);
  u16* dst = xb + (size_t)row * DSZ + d0;
  dst[0] = o0; dst[1] = o1; dst[2] = o2; dst[3] = o3;
}

// ---------------- QKV projection GEMM -> q/k/v [B,H,S,HS] bf16 ----------------
__global__ __launch_bounds__(256) void k_qkv(const u16* __restrict__ xb,
                                             const u16* __restrict__ wqT, const u16* __restrict__ wkT,
                                             const u16* __restrict__ wvT,
                                             u16* __restrict__ qo, u16* __restrict__ ko, u16* __restrict__ vo) {
  const int z = blockIdx.z;
  const u16* WT = (z == 0) ? wqT : (z == 1) ? wkT : wvT;   // [H,HS,D] k-contiguous
  u16* O = (z == 0) ? qo : (z == 1) ? ko : vo;
  const int rb = blockIdx.x * 64;
  const int h  = blockIdx.y;
  __shared__ u16 xt[64 * 40];   // [row][k] BK=32, pad 8
  __shared__ u16 wt[64 * 40];   // [col e][k]
  const int tid = threadIdx.x;
  const int lane = tid & 63, w = tid >> 6;
  const int g = lane >> 4, c = lane & 15;
  f32x4 acc[4] = {};
  for (int kt = 0; kt < DSZ / 32; ++kt) {
    const int kb = kt * 32;
    { // stage x: 64 rows x 32 k (one b128 per thread)
      int r = tid >> 2, c8 = (tid & 3) * 8;
      *(bf16x8*)&xt[r * 40 + c8] = *(const bf16x8*)&xb[(size_t)(rb + r) * DSZ + kb + c8];
      // stage W: 64 cols x 32 k
      *(bf16x8*)&wt[r * 40 + c8] = *(const bf16x8*)&WT[((size_t)h * HSZ + r) * DSZ + kb + c8];
    }
    __syncthreads();
    bf16x8 a = *(const bf16x8*)&xt[(w * 16 + c) * 40 + g * 8];
#pragma unroll
    for (int t = 0; t < 4; ++t) {
      bf16x8 bfr = *(const bf16x8*)&wt[(t * 16 + c) * 40 + g * 8];
      acc[t] = __builtin_amdgcn_mfma_f32_16x16x32_bf16(a, bfr, acc[t], 0, 0, 0);
    }
    __syncthreads();
  }
#pragma unroll
  for (int t = 0; t < 4; ++t)
#pragma unroll
    for (int r = 0; r < 4; ++r) {
      int grow = rb + w * 16 + g * 4 + r;
      int b = grow >> 11, s = grow & (SSZ - 1);
      O[(((size_t)b * NH + h) * SSZ + s) * HSZ + t * 16 + c] = f2bf(acc[t][r]);
    }
}

// ---------------- flash attention: per (b,h,64-row q block) ----------------
__global__ __launch_bounds__(256) void k_attn(const u16* __restrict__ qm, const u16* __restrict__ km,
                                              const u16* __restrict__ vm, u16* __restrict__ att) {
  const int qb = blockIdx.x * 64;
  const int h = blockIdx.y, b = blockIdx.z;
  const size_t base = ((size_t)(b * NH + h)) * SSZ * HSZ;
  __shared__ u16 Kt[32 * 72];        // [key][hs] pad 8
  __shared__ u16 Vt[64 * 40];        // [hs][key] transposed, pad 8
  __shared__ u16 Pt[4][16 * 40];     // per-wave P tile [q][key]
  const int tid = threadIdx.x, lane = tid & 63, w = tid >> 6;
  const int g = lane >> 4, c = lane & 15;
  const int wq = qb + w * 16;
  const bf16x8 a0 = *(const bf16x8*)&qm[base + (size_t)(wq + c) * HSZ + g * 8];
  const bf16x8 a1 = *(const bf16x8*)&qm[base + (size_t)(wq + c) * HSZ + 32 + g * 8];
  f32x4 o[4] = {};
  float m[4], l[4];
#pragma unroll
  for (int r = 0; r < 4; ++r) { m[r] = -1e30f; l[r] = 0.f; }
  const int nkt = (qb + 64) / 32;
  for (int kt = 0; kt < nkt; ++kt) {
    const int kb = kt * 32;
    { // stage K tile + V tile (transposed)
      int r = tid >> 3, cc = (tid & 7) * 8;
      *(bf16x8*)&Kt[r * 72 + cc] = *(const bf16x8*)&km[base + (size_t)(kb + r) * HSZ + cc];
      bf16x8 vv = *(const bf16x8*)&vm[base + (size_t)(kb + r) * HSZ + cc];
#pragma unroll
      for (int j = 0; j < 8; ++j) Vt[(cc + j) * 40 + r] = (u16)vv[j];
    }
    __syncthreads();
    if (kb <= wq + 15) {
      f32x4 c0 = {}, c1 = {};
      {
        bf16x8 b00 = *(const bf16x8*)&Kt[c * 72 + g * 8];
        bf16x8 b01 = *(const bf16x8*)&Kt[c * 72 + 32 + g * 8];
        bf16x8 b10 = *(const bf16x8*)&Kt[(16 + c) * 72 + g * 8];
        bf16x8 b11 = *(const bf16x8*)&Kt[(16 + c) * 72 + 32 + g * 8];
        c0 = __builtin_amdgcn_mfma_f32_16x16x32_bf16(a0, b00, c0, 0, 0, 0);
        c0 = __builtin_amdgcn_mfma_f32_16x16x32_bf16(a1, b01, c0, 0, 0, 0);
        c1 = __builtin_amdgcn_mfma_f32_16x16x32_bf16(a0, b10, c1, 0, 0, 0);
        c1 = __builtin_amdgcn_mfma_f32_16x16x32_bf16(a1, b11, c1, 0, 0, 0);
      }
      float p0[4], p1[4];
#pragma unroll
      for (int r = 0; r < 4; ++r) {
        const int qg = wq + g * 4 + r;
        float s0 = (kb + c <= qg) ? c0[r] : -1e30f;
        float s1 = (kb + 16 + c <= qg) ? c1[r] : -1e30f;
        float tm = fmaxf(s0, s1);
        tm = fmaxf(tm, __shfl_xor(tm, 1));
        tm = fmaxf(tm, __shfl_xor(tm, 2));
        tm = fmaxf(tm, __shfl_xor(tm, 4));
        tm = fmaxf(tm, __shfl_xor(tm, 8));
        const float mn = fmaxf(m[r], tm);
        const float sc = __expf(m[r] - mn);
        p0[r] = __expf(s0 - mn);
        p1[r] = __expf(s1 - mn);
        float sum = p0[r] + p1[r];
        sum += __shfl_xor(sum, 1);
        sum += __shfl_xor(sum, 2);
        sum += __shfl_xor(sum, 4);
        sum += __shfl_xor(sum, 8);
        l[r] = l[r] * sc + sum;
        m[r] = mn;
#pragma unroll
        for (int t = 0; t < 4; ++t) o[t][r] *= sc;
      }
#pragma unroll
      for (int r = 0; r < 4; ++r) {
        Pt[w][(g * 4 + r) * 40 + c]      = f2bf(p0[r]);
        Pt[w][(g * 4 + r) * 40 + 16 + c] = f2bf(p1[r]);
      }
      // same-wave LDS write->read: DS ops execute in order per wave
      bf16x8 pa = *(const bf16x8*)&Pt[w][c * 40 + g * 8];
#pragma unroll
      for (int t = 0; t < 4; ++t) {
        bf16x8 bv = *(const bf16x8*)&Vt[(t * 16 + c) * 40 + g * 8];
        o[t] = __builtin_amdgcn_mfma_f32_16x16x32_bf16(pa, bv, o[t], 0, 0, 0);
      }
    }
    __syncthreads();
  }
#pragma unroll
  for (int r = 0; r < 4; ++r) {
    const float inv = 1.f / l[r];
    const int srow = b * SSZ + wq + g * 4 + r;   // [B*S, D] row
#pragma unroll
    for (int t = 0; t < 4; ++t)
      att[(size_t)srow * DSZ + h * HSZ + t * 16 + c] = f2bf(o[t][r] * inv);
  }
}

// ------------- logits GEMM [8192,512]@[512,32000] + fused per-tile logsumexp partials -------------
__global__ __launch_bounds__(256) void k_logits(const u16* __restrict__ att, const u16* __restrict__ woT,
                                                float* __restrict__ logits,
                                                float* __restrict__ pmax, float* __restrict__ psum) {
  const int rb = blockIdx.x * 128;
  const int vb = blockIdx.y * 128;
  __shared__ u16 At[128 * 40];   // [row][k] BK=32
  __shared__ u16 Bt[128 * 40];   // [col][k]
  const int tid = threadIdx.x, lane = tid & 63, w = tid >> 6;
  const int wr = w >> 1, wc = w & 1;
  const int g = lane >> 4, c = lane & 15;
  f32x4 acc[4][4] = {};
  for (int kt = 0; kt < DSZ / 32; ++kt) {
    const int kb = kt * 32;
#pragma unroll
    for (int i = 0; i < 2; ++i) {   // stage A + B, b128 both sides
      int id = tid + i * 256;
      int r = id >> 2, c8 = (id & 3) * 8;
      *(bf16x8*)&At[r * 40 + c8] = *(const bf16x8*)&att[(size_t)(rb + r) * DSZ + kb + c8];
      *(bf16x8*)&Bt[r * 40 + c8] = *(const bf16x8*)&woT[(size_t)(vb + r) * DSZ + kb + c8];
    }
    __syncthreads();
    bf16x8 af[4], bf[4];
#pragma unroll
    for (int i = 0; i < 4; ++i) af[i] = *(const bf16x8*)&At[(wr * 64 + i * 16 + c) * 40 + g * 8];
#pragma unroll
    for (int j = 0; j < 4; ++j) bf[j] = *(const bf16x8*)&Bt[(wc * 64 + j * 16 + c) * 40 + g * 8];
#pragma unroll
    for (int i = 0; i < 4; ++i)
#pragma unroll
      for (int j = 0; j < 4; ++j)
        acc[i][j] = __builtin_amdgcn_mfma_f32_16x16x32_bf16(af[i], bf[j], acc[i][j], 0, 0, 0);
    __syncthreads();
  }
  // epilogue: write logits + per-row (max, sumexp) partial for this 64-col strip
#pragma unroll
  for (int i = 0; i < 4; ++i) {
#pragma unroll
    for (int r = 0; r < 4; ++r) {
      const int row = rb + wr * 64 + i * 16 + g * 4 + r;
      float mx = -1e30f;
#pragma unroll
      for (int j = 0; j < 4; ++j) mx = fmaxf(mx, acc[i][j][r]);
#pragma unroll
      for (int j = 0; j < 4; ++j)
        logits[(size_t)row * VSZ + vb + wc * 64 + j * 16 + c] = acc[i][j][r];
      mx = fmaxf(mx, __shfl_xor(mx, 1));
      mx = fmaxf(mx, __shfl_xor(mx, 2));
      mx = fmaxf(mx, __shfl_xor(mx, 4));
      mx = fmaxf(mx, __shfl_xor(mx, 8));
      float sm = 0.f;
#pragma unroll
      for (int j = 0; j < 4; ++j) sm += __expf(acc[i][j][r] - mx);
      sm += __shfl_xor(sm, 1);
      sm += __shfl_xor(sm, 2);
      sm += __shfl_xor(sm, 4);
      sm += __shfl_xor(sm, 8);
      if (c == 0) {
        const int tn = blockIdx.y * 2 + wc;
        pmax[(size_t)row * NT + tn] = mx;
        psum[(size_t)row * NT + tn] = sm;
      }
    }
  }
}

// ---------------- finalize: lse per row, gather target logit, mean-NLL ----------------
__global__ __launch_bounds__(256) void k_lse_loss(const float* __restrict__ pmax, const float* __restrict__ psum,
                                                  const float* __restrict__ logits, const int* __restrict__ target,
                                                  float* __restrict__ loss) {
  const int lane = threadIdx.x & 63, w = threadIdx.x >> 6;
  const int row = blockIdx.x * 4 + w;
  float me[8], se[8];
#pragma unroll
  for (int j = 0; j < 8; ++j) {
    const int e = lane + j * 64;
    if (e < NT) { me[j] = pmax[(size_t)row * NT + e]; se[j] = psum[(size_t)row * NT + e]; }
    else        { me[j] = -1e30f; se[j] = 0.f; }
  }
  float M = -1e30f;
#pragma unroll
  for (int j = 0; j < 8; ++j) M = fmaxf(M, me[j]);
#pragma unroll
  for (int mask = 1; mask < 64; mask <<= 1) M = fmaxf(M, __shfl_xor(M, mask));
  float Ssum = 0.f;
#pragma unroll
  for (int j = 0; j < 8; ++j) Ssum += se[j] * __expf(me[j] - M);
#pragma unroll
  for (int mask = 1; mask < 64; mask <<= 1) Ssum += __shfl_xor(Ssum, mask);
  if (lane == 0) {
    const float L = M + logf(Ssum);
    const int tgt = target[row];
    const float lt = logits[(size_t)row * VSZ + tgt];
    atomicAdd(loss, (L - lt) * (1.0f / NROWS));
  }
}

extern "C" void kernel_launch(void* const* d_in, const int* in_sizes, int n_in,
                              void* d_out, int out_size, void* d_ws, size_t ws_size,
                              hipStream_t stream) {
  const int*   index  = (const int*)d_in[0];
  const int*   target = (const int*)d_in[1];
  const float* tok    = (const float*)d_in[2];
  const float* pos    = (const float*)d_in[3];
  const float* Wq     = (const float*)d_in[4];
  const float* Wk     = (const float*)d_in[5];
  const float* Wv     = (const float*)d_in[6];
  const float* Wo     = (const float*)d_in[7];
  float* logits = (float*)d_out;
  float* loss   = logits + (size_t)NROWS * VSZ;

  char* wsb = (char*)d_ws;
  size_t off = 0;
  auto alloc = [&](size_t bytes) { char* p = wsb + off; off += (bytes + 255) & ~(size_t)255; return p; };
  u16* xb  = (u16*)alloc((size_t)NROWS * DSZ * 2);
  u16* wqT = (u16*)alloc((size_t)NH * HSZ * DSZ * 2);
  u16* wkT = (u16*)alloc((size_t)NH * HSZ * DSZ * 2);
  u16* wvT = (u16*)alloc((size_t)NH * HSZ * DSZ * 2);
  u16* woT = (u16*)alloc((size_t)VSZ * DSZ * 2);
  u16* qo  = (u16*)alloc((size_t)NB * NH * SSZ * HSZ * 2);
  u16* ko  = (u16*)alloc((size_t)NB * NH * SSZ * HSZ * 2);
  u16* vo  = (u16*)alloc((size_t)NB * NH * SSZ * HSZ * 2);
  u16* att = (u16*)alloc((size_t)NROWS * DSZ * 2);
  float* pmax = (float*)alloc((size_t)NROWS * NT * 4);
  float* psum = (float*)alloc((size_t)NROWS * NT * 4);
  (void)ws_size; (void)n_in; (void)in_sizes; (void)out_size;

  k_tqkv<<<dim3(DSZ / 64, NH, 3), 256, 0, stream>>>(Wq, Wk, Wv, wqT, wkT, wvT, loss);
  k_twout<<<dim3(VSZ / 64, DSZ / 64), 256, 0, stream>>>(Wo, woT);
  k_embed<<<dim3(NROWS), 128, 0, stream>>>(index, tok, pos, xb);
  k_qkv<<<dim3(NROWS / 64, NH, 3), 256, 0, stream>>>(xb, wqT, wkT, wvT, qo, ko, vo);
  k_attn<<<dim3(SSZ / 64, NH, NB), 256, 0, stream>>>(qo, ko, vo, att);
  k_logits<<<dim3(NROWS / 128, VSZ / 128), 256, 0, stream>>>(att, woT, logits, pmax, psum);
  k_lse_loss<<<dim3(NROWS / 4), 256, 0, stream>>>(pmax, psum, logits, target, loss);
}